// Round 10
// baseline (65.483 us; speedup 1.0000x reference)
//
#include <hip/hip_runtime.h>
#include <hip/hip_bf16.h>

// QuantumFeedForward, fully fused, ZERO-LDS / ZERO-BARRIER dataflow kernel:
//   q[n,w] = prod_{v in M_w} cos(theta_v)*cos(x[n,v])   (analytic circuit collapse)
//   out    = relu(q@W1^T+b1) @ W2^T + b2
// 32x32x16 MFMA. H^T = mfma(W1aug-frag, qaug-frag) -> relu -> cvt_pk ->
// v_permlane32_swap -> GEMM A-quads, all register-resident (verified R9).
// W2 is precomputed into EXACT B-fragment order in global (k_cvt_w2f), so the
// GEMM B-operand is loaded global->register directly: no LDS, no staging, no
// s_barrier anywhere. Waves are fully independent; the compiler inserts counted
// per-use vmcnt waits (never a drain). L2 serves the 2MB W2f per XCD.

typedef __attribute__((ext_vector_type(8))) short bf16x8;
typedef __attribute__((ext_vector_type(16))) float f32x16;
typedef __attribute__((ext_vector_type(8))) unsigned short us8;
typedef unsigned int u32;

#define NTOK  16384
#define EMBED 512
#define FFN   2048
#define NQ    10
#define BM    128
#define BN    128

__device__ __forceinline__ unsigned short f2bf(float f) {
  union { float f; unsigned int u; } a; a.f = f;
  unsigned int r = a.u + 0x7FFFu + ((a.u >> 16) & 1u);   // RNE
  return (unsigned short)(r >> 16);
}

// ---- K0: W2 (512x2048 f32) -> bf16 B-fragment order ----
// W2f[((tile*128 + kb)*64 + l)*8 + e] = W2[col=tile*32+(l&31)][k=kb*16+(l>>5)*8+e]
__global__ __launch_bounds__(256) void k_cvt_w2f(const float* __restrict__ W2,
                                                 unsigned short* __restrict__ W2f) {
  int gid = blockIdx.x * 256 + threadIdx.x;   // 131072 = 16 tiles * 128 kb * 64 lanes
  int l = gid & 63, kb = (gid >> 6) & 127, tile = gid >> 13;
  int col = tile * 32 + (l & 31);
  int k0 = kb * 16 + (l >> 5) * 8;
  const float* src = W2 + (size_t)col * FFN + k0;
  float4 v0 = *(const float4*)src;
  float4 v1 = *(const float4*)(src + 4);
  us8 o;
  o[0] = f2bf(v0.x); o[1] = f2bf(v0.y); o[2] = f2bf(v0.z); o[3] = f2bf(v0.w);
  o[4] = f2bf(v1.x); o[5] = f2bf(v1.y); o[6] = f2bf(v1.z); o[7] = f2bf(v1.w);
  *(us8*)(W2f + (size_t)gid * 8) = o;
}

// ---- K0b: W1_aug -> bf16 A-frag order for 32x32x16 ----
// W1f[blk][lane][e] = W1aug[wire=(lane>>5)*8+e][k = blk*32 + (lane&31)]
__global__ __launch_bounds__(256) void k_cvt_w1f(const float* __restrict__ W1,
                                                 const float* __restrict__ b1,
                                                 unsigned short* __restrict__ W1f) {
  int gid = blockIdx.x * 256 + threadIdx.x;     // 4096 = 64 blk * 64 lanes
  int l = gid & 63, blk = gid >> 6;
  int k = blk * 32 + (l & 31);
  int wg = (l >> 5) * 8;
  us8 o;
#pragma unroll
  for (int e = 0; e < 8; ++e) {
    int wire = wg + e;
    float v = (wire < NQ) ? W1[k * NQ + wire] : (wire == NQ ? b1[k] : 0.f);
    o[e] = f2bf(v);
  }
  *(us8*)(W1f + (size_t)gid * 8) = o;
}

// ---- K0c: q_aug B-frags for 32x32x16 ----
// Qf[tile][lane][e] = qaug[wire=(lane>>5)*8+e][token = tile*32 + (lane&31)]
__global__ __launch_bounds__(256) void k_q(const float* __restrict__ x,
                                           const float* __restrict__ theta,
                                           unsigned short* __restrict__ Qf) {
  int gid = blockIdx.x * 256 + threadIdx.x;     // 32768 = 512 tiles * 64 lanes
  int l = gid & 63, tile = gid >> 6;
  int tok = tile * 32 + (l & 31), g = l >> 5;
  const int masks[NQ] = {0x2AB,0x3FD,0x3FA,0x3F5,0x3EA,0x3D5,0x3AA,0x355,0x2AA,0x155};
  float z[NQ], qv[NQ];
#pragma unroll
  for (int w = 0; w < NQ; ++w)
    z[w] = __builtin_cosf(x[(size_t)tok * EMBED + w]) * __builtin_cosf(theta[w]);
#pragma unroll
  for (int w = 0; w < NQ; ++w) {
    float p = 1.f;
#pragma unroll
    for (int v = 0; v < NQ; ++v)
      if ((masks[w] >> v) & 1) p *= z[v];
    qv[w] = p;
  }
  us8 o = (us8)0;
  if (g == 0) {
#pragma unroll
    for (int e = 0; e < 8; ++e) o[e] = f2bf(qv[e]);
  } else {
    o[0] = f2bf(qv[8]); o[1] = f2bf(qv[9]); o[2] = f2bf(1.f);
  }
  *(us8*)(Qf + (size_t)gid * 8) = o;
}

// ---------------- K1: fused H-gen + GEMM, no LDS / no barriers ----------------
__global__ __launch_bounds__(256, 2) void k_fused(const unsigned short* __restrict__ Qf,
                                                  const unsigned short* __restrict__ W1f,
                                                  const unsigned short* __restrict__ W2f,
                                                  const float* __restrict__ b2,
                                                  float* __restrict__ out) {
  // XCD-aware bijective swizzle: 512 blocks, 64 consecutive per XCD; n fastest
  // (each XCD touches the full 2MB W2f -> L2-resident).
  int bid = blockIdx.x;
  int swz = (bid & 7) * 64 + (bid >> 3);
  const int m0 = (swz >> 2) * BM;
  const int n0 = (swz & 3) * BN;
  const int tid  = threadIdx.x;
  const int lane = tid & 63;
  const int wave = tid >> 6;           // 4 waves: 2 (M) x 2 (N), 64x64 tiles
  const int wm = wave >> 1, wn = wave & 1;
  const int h = lane >> 5, t31 = lane & 31;

  // q_aug B-frags for this wave's 2 token-tiles of 32
  bf16x8 qf[2];
#pragma unroll
  for (int i = 0; i < 2; ++i)
    qf[i] = *(const bf16x8*)&Qf[(((size_t)(m0 >> 5) + wm * 2 + i) * 64 + lane) * 8];

  f32x16 acc[2][2] = {};
  bf16x8 wfE[2], wfO[2];               // W1aug frags, even/odd kt
  bf16x8 aqA[2][2][2], aqB[2][2][2];   // GEMM A-quads, even/odd kt parity
  bf16x8 bgA[8], bgB[8];               // B-frags: even/odd half of current pair

#define WLOAD(KT, WF)                                                           \
  { _Pragma("unroll")                                                           \
    for (int b = 0; b < 2; ++b)                                                 \
      WF[b] = *(const bf16x8*)&W1f[(((size_t)(KT) * 2 + b) * 64 + lane) * 8]; }

  // 8 B-frag loads for pair P, half HF (HF=0: kt=2P, HF=1: kt=2P+1)
#define BGLOAD(P, HF, BG)                                                       \
  { _Pragma("unroll")                                                           \
    for (int r = 0; r < 8; ++r) {                                               \
      int j = r >> 2, s = r & 3;                                                \
      int tile = (n0 >> 5) + wn * 2 + j;                                        \
      int kb = (P) * 8 + (HF) * 4 + s;                                          \
      BG[r] = *(const bf16x8*)&W2f[(((size_t)tile * 128 + kb) * 64 + lane) * 8]; \
    } }

  // H^T = mfma(W1aug, qaug); relu; cvt_pk; permlane32_swap -> A-quads (registers)
#define HGEN(AQ, WF)                                                            \
  { _Pragma("unroll")                                                           \
    for (int i = 0; i < 2; ++i) {                                               \
      _Pragma("unroll")                                                         \
      for (int b = 0; b < 2; ++b) {                                             \
        f32x16 zz = {};                                                         \
        f32x16 d = __builtin_amdgcn_mfma_f32_32x32x16_bf16(WF[b], qf[i], zz, 0, 0, 0); \
        u32 dw0, dw1, dw2, dw3, dw4, dw5, dw6, dw7;                             \
        { float a0=fmaxf(d[0],0.f),a1=fmaxf(d[1],0.f);                          \
          asm("v_cvt_pk_bf16_f32 %0, %1, %2":"=v"(dw0):"v"(a0),"v"(a1)); }      \
        { float a0=fmaxf(d[2],0.f),a1=fmaxf(d[3],0.f);                          \
          asm("v_cvt_pk_bf16_f32 %0, %1, %2":"=v"(dw1):"v"(a0),"v"(a1)); }      \
        { float a0=fmaxf(d[4],0.f),a1=fmaxf(d[5],0.f);                          \
          asm("v_cvt_pk_bf16_f32 %0, %1, %2":"=v"(dw2):"v"(a0),"v"(a1)); }      \
        { float a0=fmaxf(d[6],0.f),a1=fmaxf(d[7],0.f);                          \
          asm("v_cvt_pk_bf16_f32 %0, %1, %2":"=v"(dw3):"v"(a0),"v"(a1)); }      \
        { float a0=fmaxf(d[8],0.f),a1=fmaxf(d[9],0.f);                          \
          asm("v_cvt_pk_bf16_f32 %0, %1, %2":"=v"(dw4):"v"(a0),"v"(a1)); }      \
        { float a0=fmaxf(d[10],0.f),a1=fmaxf(d[11],0.f);                        \
          asm("v_cvt_pk_bf16_f32 %0, %1, %2":"=v"(dw5):"v"(a0),"v"(a1)); }      \
        { float a0=fmaxf(d[12],0.f),a1=fmaxf(d[13],0.f);                        \
          asm("v_cvt_pk_bf16_f32 %0, %1, %2":"=v"(dw6):"v"(a0),"v"(a1)); }      \
        { float a0=fmaxf(d[14],0.f),a1=fmaxf(d[15],0.f);                        \
          asm("v_cvt_pk_bf16_f32 %0, %1, %2":"=v"(dw7):"v"(a0),"v"(a1)); }      \
        asm("v_permlane32_swap_b32 %0, %1" : "+v"(dw0), "+v"(dw2));             \
        asm("v_permlane32_swap_b32 %0, %1" : "+v"(dw1), "+v"(dw3));             \
        asm("v_permlane32_swap_b32 %0, %1" : "+v"(dw4), "+v"(dw6));             \
        asm("v_permlane32_swap_b32 %0, %1" : "+v"(dw5), "+v"(dw7));             \
        union { u32 u[4]; bf16x8 v; } u0, u1;                                   \
        u0.u[0]=dw0; u0.u[1]=dw1; u0.u[2]=dw2; u0.u[3]=dw3;                     \
        u1.u[0]=dw4; u1.u[1]=dw5; u1.u[2]=dw6; u1.u[3]=dw7;                     \
        AQ[i][b][0] = u0.v; AQ[i][b][1] = u1.v;                                 \
      } } }

  // 16 MFMA consuming one kt: A-quads AQ, B-frags BG (s = b*2+sb = 0..3)
#define GEMMKT(AQ, BG)                                                          \
  { __builtin_amdgcn_s_setprio(1);                                              \
    _Pragma("unroll")                                                           \
    for (int s = 0; s < 4; ++s) {                                               \
      acc[0][0] = __builtin_amdgcn_mfma_f32_32x32x16_bf16(AQ[0][s >> 1][s & 1], BG[s],     acc[0][0], 0, 0, 0); \
      acc[0][1] = __builtin_amdgcn_mfma_f32_32x32x16_bf16(AQ[0][s >> 1][s & 1], BG[4 + s], acc[0][1], 0, 0, 0); \
      acc[1][0] = __builtin_amdgcn_mfma_f32_32x32x16_bf16(AQ[1][s >> 1][s & 1], BG[s],     acc[1][0], 0, 0, 0); \
      acc[1][1] = __builtin_amdgcn_mfma_f32_32x32x16_bf16(AQ[1][s >> 1][s & 1], BG[4 + s], acc[1][1], 0, 0, 0); \
    }                                                                           \
    __builtin_amdgcn_s_setprio(0); }

  // ---- prologue ----
  WLOAD(0, wfE);
  WLOAD(1, wfO);
  BGLOAD(0, 0, bgA);                   // pair 0 even half
  HGEN(aqA, wfE);                      // kt 0 (covers bgA latency)

  // ---- main loop: one K-pair (2 kt of 64 k) per iteration; no barriers ----
  for (int p = 0; p < 16; ++p) {
    BGLOAD(p, 1, bgB);                 // odd half of pair p
    if (p < 15) WLOAD(2 * p + 2, wfE);
    GEMMKT(aqA, bgA);                  // kt = 2p
    HGEN(aqB, wfO);                    // kt = 2p+1 (covers bgB latency)
    if (p < 15) { BGLOAD(p + 1, 0, bgA); WLOAD(2 * p + 3, wfO); }
    GEMMKT(aqB, bgB);                  // kt = 2p+1
    if (p < 15) HGEN(aqA, wfE);        // kt = 2p+2 (covers next bgA latency)
  }

  // ---- epilogue: out = acc + b2 ----
#pragma unroll
  for (int j = 0; j < 2; ++j) {
    const int col = n0 + wn * 64 + j * 32 + t31;
    const float bbv = b2[col];
#pragma unroll
    for (int i = 0; i < 2; ++i) {
#pragma unroll
      for (int r = 0; r < 16; ++r) {
        int tok = m0 + wm * 64 + i * 32 + (r & 3) + 8 * (r >> 2) + 4 * h;
        out[(size_t)tok * EMBED + col] = acc[i][j][r] + bbv;
      }
    }
  }
#undef WLOAD
#undef BGLOAD
#undef HGEN
#undef GEMMKT
}

extern "C" void kernel_launch(void* const* d_in, const int* in_sizes, int n_in,
                              void* d_out, int out_size, void* d_ws, size_t ws_size,
                              hipStream_t stream) {
  const float* x     = (const float*)d_in[0];
  const float* theta = (const float*)d_in[1];
  const float* W1    = (const float*)d_in[2];
  const float* b1    = (const float*)d_in[3];
  const float* W2    = (const float*)d_in[4];
  const float* b2    = (const float*)d_in[5];
  float* out = (float*)d_out;

  char* ws = (char*)d_ws;
  unsigned short* W2f = (unsigned short*)ws;                          // 2 MB
  unsigned short* W1f = (unsigned short*)(ws + (2u << 20));           // 64 KB
  unsigned short* Qfg = (unsigned short*)(ws + (2u << 20) + (64u << 10)); // 512 KB

  k_cvt_w2f<<<512, 256, 0, stream>>>(W2, W2f);
  k_cvt_w1f<<<16, 256, 0, stream>>>(W1, b1, W1f);
  k_q      <<<128, 256, 0, stream>>>(x, theta, Qfg);
  k_fused  <<<(NTOK / BM) * (EMBED / BN), 256, 0, stream>>>(Qfg, W1f, W2f, b2, out);
}

// Round 11
// 57.440 us; speedup vs baseline: 1.1400x; 1.1400x over previous
//
#include <hip/hip_runtime.h>
#include <hip/hip_bf16.h>

// QuantumFeedForward, fully fused:
//   q[n,w] = prod_{v in M_w} cos(theta_v)*cos(x[n,v])   (analytic circuit collapse)
//   out    = relu(q@W1^T+b1) @ W2^T + b2
// 32x32x16 MFMA. H^T = mfma(W1aug-frag, qaug-frag) -> relu -> cvt_pk ->
// v_permlane32_swap -> GEMM A-quads in registers (verified R9/R10).
// KEY CHANGE (R11): 4 waves/SIMD. 512-thread blocks, wave tile 32 tok x 64 cols
// -> 4096 waves total (vs 2048 in every prior round). W2 B-frags LDS-staged in
// FRAGMENT order (linear = gload_lds-legal and conflict-free ds_read, no swizzle).
// Sync: one raw s_barrier + one precise vmcnt(0) per 64-k tile; stage post-barrier.

typedef __attribute__((ext_vector_type(8))) short bf16x8;
typedef __attribute__((ext_vector_type(16))) float f32x16;
typedef __attribute__((ext_vector_type(8))) unsigned short us8;
typedef unsigned int u32;

#define NTOK  16384
#define EMBED 512
#define FFN   2048
#define NQ    10
#define BM    128
#define BN    128
#define NKT   32          // K-tiles of 64 k

__device__ __forceinline__ unsigned short f2bf(float f) {
  union { float f; unsigned int u; } a; a.f = f;
  unsigned int r = a.u + 0x7FFFu + ((a.u >> 16) & 1u);   // RNE
  return (unsigned short)(r >> 16);
}

__device__ __forceinline__ void gload_lds16(const void* g, void* l) {
  __builtin_amdgcn_global_load_lds(
      (const __attribute__((address_space(1))) unsigned int*)g,
      (__attribute__((address_space(3))) unsigned int*)l, 16, 0, 0);
}

// ---------------- K0: fused prep (W2f + Qf + W1f), one launch ----------------
// W2f[((tile*128+kb)*64+l)*8+e] = W2[col=tile*32+(l&31)][k=kb*16+(l>>5)*8+e]
// Qf [(tile*64+l)*8+e]          = qaug[wire=(l>>5)*8+e][token=tile*32+(l&31)]
// W1f[(blk*64+l)*8+e]           = W1aug[wire=(l>>5)*8+e][k=blk*32+(l&31)]
__global__ __launch_bounds__(256) void k_prep(const float* __restrict__ x,
                                              const float* __restrict__ theta,
                                              const float* __restrict__ W1,
                                              const float* __restrict__ b1,
                                              const float* __restrict__ W2,
                                              unsigned short* __restrict__ W2f,
                                              unsigned short* __restrict__ W1f,
                                              unsigned short* __restrict__ Qf) {
  int bb = blockIdx.x;
  if (bb < 512) {                       // ---- W2f: 131072 chunks ----
    int gid = bb * 256 + threadIdx.x;
    int l = gid & 63, kb = (gid >> 6) & 127, tile = gid >> 13;
    int col = tile * 32 + (l & 31);
    int k0 = kb * 16 + (l >> 5) * 8;
    const float* src = W2 + (size_t)col * FFN + k0;
    float4 v0 = *(const float4*)src;
    float4 v1 = *(const float4*)(src + 4);
    us8 o;
    o[0] = f2bf(v0.x); o[1] = f2bf(v0.y); o[2] = f2bf(v0.z); o[3] = f2bf(v0.w);
    o[4] = f2bf(v1.x); o[5] = f2bf(v1.y); o[6] = f2bf(v1.z); o[7] = f2bf(v1.w);
    *(us8*)(W2f + (size_t)gid * 8) = o;
  } else if (bb < 640) {                // ---- Qf: 32768 chunks ----
    int gid = (bb - 512) * 256 + threadIdx.x;
    int l = gid & 63, tile = gid >> 6;
    int tok = tile * 32 + (l & 31), g = l >> 5;
    const int masks[NQ] = {0x2AB,0x3FD,0x3FA,0x3F5,0x3EA,0x3D5,0x3AA,0x355,0x2AA,0x155};
    float z[NQ], qv[NQ];
#pragma unroll
    for (int w = 0; w < NQ; ++w)
      z[w] = __builtin_cosf(x[(size_t)tok * EMBED + w]) * __builtin_cosf(theta[w]);
#pragma unroll
    for (int w = 0; w < NQ; ++w) {
      float p = 1.f;
#pragma unroll
      for (int v = 0; v < NQ; ++v)
        if ((masks[w] >> v) & 1) p *= z[v];
      qv[w] = p;
    }
    us8 o = (us8)0;
    if (g == 0) {
#pragma unroll
      for (int e = 0; e < 8; ++e) o[e] = f2bf(qv[e]);
    } else {
      o[0] = f2bf(qv[8]); o[1] = f2bf(qv[9]); o[2] = f2bf(1.f);
    }
    *(us8*)(Qf + (size_t)gid * 8) = o;
  } else {                              // ---- W1f: 4096 chunks ----
    int gid = (bb - 640) * 256 + threadIdx.x;
    int l = gid & 63, blk = gid >> 6;
    int k = blk * 32 + (l & 31);
    int wg = (l >> 5) * 8;
    us8 o;
#pragma unroll
    for (int e = 0; e < 8; ++e) {
      int wire = wg + e;
      float v = (wire < NQ) ? W1[k * NQ + wire] : (wire == NQ ? b1[k] : 0.f);
      o[e] = f2bf(v);
    }
    *(us8*)(W1f + (size_t)gid * 8) = o;
  }
}

// ---------------- K1: fused H-gen + GEMM, 4 waves/SIMD ----------------
__global__ __launch_bounds__(512, 4) void k_fused(const unsigned short* __restrict__ Qf,
                                                  const unsigned short* __restrict__ W1f,
                                                  const unsigned short* __restrict__ W2f,
                                                  const float* __restrict__ b2,
                                                  float* __restrict__ out) {
  __shared__ short Bw[2][16 * 64 * 8];   // 2 x 16KB: [tile2*4+kb][lane][8], frag order
  __shared__ short W1s[2][2 * 64 * 8];   // 2 x 2KB:  [b][lane][8]

  // XCD-aware bijective swizzle: 512 blocks, 64 consecutive per XCD; n fastest.
  int bid = blockIdx.x;
  int swz = (bid & 7) * 64 + (bid >> 3);
  const int m0 = (swz >> 2) * BM;
  const int n0 = (swz & 3) * BN;
  const int tid  = threadIdx.x;
  const int lane = tid & 63;
  const int wave = tid >> 6;           // 8 waves: 4 (M) x 2 (N), 32x64 tiles
  const int wm = wave >> 1, wn = wave & 1;
  const int h = lane >> 5, t31 = lane & 31;
  const int nt0 = n0 >> 5;             // global col-tile base (4 tiles of 32)

  // q_aug B-frag for this wave's 32 tokens (single load, register-resident)
  bf16x8 qf = *(const bf16x8*)&Qf[(((size_t)(m0 >> 5) + wm) * 64 + lane) * 8];

  f32x16 acc[2] = {};

  // Stage one 64-k tile: 1024 Bw chunks (2/thread) + 128 W1 chunks (waves 0-1).
#define STAGE(KT, B)                                                            \
  { _Pragma("unroll")                                                           \
    for (int hf = 0; hf < 2; ++hf) {                                            \
      int ch = hf * 512 + tid;                                                  \
      int tile2 = ch >> 8, kb = (ch >> 6) & 3, ln = ch & 63;                    \
      gload_lds16(&W2f[(((size_t)(nt0 + tile2) * 128 + (KT) * 4 + kb) * 64 + ln) * 8], \
                  &Bw[B][ch * 8]);                                              \
    }                                                                           \
    if (tid < 128)                                                              \
      gload_lds16(&W1f[(((size_t)(KT) * 2 + (tid >> 6)) * 64 + (tid & 63)) * 8],\
                  &W1s[B][tid * 8]); }

  // H^T = mfma(W1aug, qaug); relu; cvt_pk; permlane32_swap -> A-quads (registers)
#define HGEN1(WF, AQ0, AQ1)                                                     \
  { f32x16 zz = {};                                                             \
    f32x16 d = __builtin_amdgcn_mfma_f32_32x32x16_bf16((WF), qf, zz, 0, 0, 0);  \
    u32 dw0, dw1, dw2, dw3, dw4, dw5, dw6, dw7;                                 \
    { float a0=fmaxf(d[0],0.f),a1=fmaxf(d[1],0.f);                              \
      asm("v_cvt_pk_bf16_f32 %0, %1, %2":"=v"(dw0):"v"(a0),"v"(a1)); }          \
    { float a0=fmaxf(d[2],0.f),a1=fmaxf(d[3],0.f);                              \
      asm("v_cvt_pk_bf16_f32 %0, %1, %2":"=v"(dw1):"v"(a0),"v"(a1)); }          \
    { float a0=fmaxf(d[4],0.f),a1=fmaxf(d[5],0.f);                              \
      asm("v_cvt_pk_bf16_f32 %0, %1, %2":"=v"(dw2):"v"(a0),"v"(a1)); }          \
    { float a0=fmaxf(d[6],0.f),a1=fmaxf(d[7],0.f);                              \
      asm("v_cvt_pk_bf16_f32 %0, %1, %2":"=v"(dw3):"v"(a0),"v"(a1)); }          \
    { float a0=fmaxf(d[8],0.f),a1=fmaxf(d[9],0.f);                              \
      asm("v_cvt_pk_bf16_f32 %0, %1, %2":"=v"(dw4):"v"(a0),"v"(a1)); }          \
    { float a0=fmaxf(d[10],0.f),a1=fmaxf(d[11],0.f);                            \
      asm("v_cvt_pk_bf16_f32 %0, %1, %2":"=v"(dw5):"v"(a0),"v"(a1)); }          \
    { float a0=fmaxf(d[12],0.f),a1=fmaxf(d[13],0.f);                            \
      asm("v_cvt_pk_bf16_f32 %0, %1, %2":"=v"(dw6):"v"(a0),"v"(a1)); }          \
    { float a0=fmaxf(d[14],0.f),a1=fmaxf(d[15],0.f);                            \
      asm("v_cvt_pk_bf16_f32 %0, %1, %2":"=v"(dw7):"v"(a0),"v"(a1)); }          \
    asm("v_permlane32_swap_b32 %0, %1" : "+v"(dw0), "+v"(dw2));                 \
    asm("v_permlane32_swap_b32 %0, %1" : "+v"(dw1), "+v"(dw3));                 \
    asm("v_permlane32_swap_b32 %0, %1" : "+v"(dw4), "+v"(dw6));                 \
    asm("v_permlane32_swap_b32 %0, %1" : "+v"(dw5), "+v"(dw7));                 \
    union { u32 u[4]; bf16x8 v; } u0, u1;                                       \
    u0.u[0]=dw0; u0.u[1]=dw1; u0.u[2]=dw2; u0.u[3]=dw3;                         \
    u1.u[0]=dw4; u1.u[1]=dw5; u1.u[2]=dw6; u1.u[3]=dw7;                         \
    AQ0 = u0.v; AQ1 = u1.v; }

  // ---- prologue: stage tile 0 ----
  STAGE(0, 0);

  // ---- main loop: one 64-k tile per iteration ----
  for (int kt = 0; kt < NKT; ++kt) {
    const int cur = kt & 1;
    asm volatile("s_waitcnt vmcnt(0)" ::: "memory");   // stage(kt) landed (precise)
    __builtin_amdgcn_s_barrier();                      // all waves done with buf cur^1
    asm volatile("" ::: "memory");
    if (kt + 1 < NKT) STAGE(kt + 1, cur ^ 1);          // post-barrier: race-safe

    // W1 frags for this tile (LDS, broadcast-ish b128)
    bf16x8 wf0 = *(const bf16x8*)&W1s[cur][(0 * 64 + lane) * 8];
    bf16x8 wf1 = *(const bf16x8*)&W1s[cur][(1 * 64 + lane) * 8];
    // HGEN: 2 mfma -> 4 A-quads (aq[b][sb], kb-local = b*2+sb)
    bf16x8 aq00, aq01, aq10, aq11;
    HGEN1(wf0, aq00, aq01);
    HGEN1(wf1, aq10, aq11);

    // GEMM: j = 0,1 col-tiles; s = kb-local 0..3 pairs with aq[s>>1][s&1]
#pragma unroll
    for (int j = 0; j < 2; ++j) {
      bf16x8 bg0 = *(const bf16x8*)&Bw[cur][(((wn * 2 + j) * 4 + 0) * 64 + lane) * 8];
      bf16x8 bg1 = *(const bf16x8*)&Bw[cur][(((wn * 2 + j) * 4 + 1) * 64 + lane) * 8];
      bf16x8 bg2 = *(const bf16x8*)&Bw[cur][(((wn * 2 + j) * 4 + 2) * 64 + lane) * 8];
      bf16x8 bg3 = *(const bf16x8*)&Bw[cur][(((wn * 2 + j) * 4 + 3) * 64 + lane) * 8];
      __builtin_amdgcn_s_setprio(1);
      acc[j] = __builtin_amdgcn_mfma_f32_32x32x16_bf16(aq00, bg0, acc[j], 0, 0, 0);
      acc[j] = __builtin_amdgcn_mfma_f32_32x32x16_bf16(aq01, bg1, acc[j], 0, 0, 0);
      acc[j] = __builtin_amdgcn_mfma_f32_32x32x16_bf16(aq10, bg2, acc[j], 0, 0, 0);
      acc[j] = __builtin_amdgcn_mfma_f32_32x32x16_bf16(aq11, bg3, acc[j], 0, 0, 0);
      __builtin_amdgcn_s_setprio(0);
    }
  }

  // ---- epilogue: out = acc + b2 ----
#pragma unroll
  for (int j = 0; j < 2; ++j) {
    const int col = n0 + wn * 64 + j * 32 + t31;
    const float bbv = b2[col];
#pragma unroll
    for (int r = 0; r < 16; ++r) {
      int tok = m0 + wm * 32 + (r & 3) + 8 * (r >> 2) + 4 * h;
      out[(size_t)tok * EMBED + col] = acc[j][r] + bbv;
    }
  }
#undef STAGE
#undef HGEN1
}

extern "C" void kernel_launch(void* const* d_in, const int* in_sizes, int n_in,
                              void* d_out, int out_size, void* d_ws, size_t ws_size,
                              hipStream_t stream) {
  const float* x     = (const float*)d_in[0];
  const float* theta = (const float*)d_in[1];
  const float* W1    = (const float*)d_in[2];
  const float* b1    = (const float*)d_in[3];
  const float* W2    = (const float*)d_in[4];
  const float* b2    = (const float*)d_in[5];
  float* out = (float*)d_out;

  char* ws = (char*)d_ws;
  unsigned short* W2f = (unsigned short*)ws;                          // 2 MB
  unsigned short* W1f = (unsigned short*)(ws + (2u << 20));           // 64 KB
  unsigned short* Qfg = (unsigned short*)(ws + (2u << 20) + (64u << 10)); // 512 KB

  k_prep <<<656, 256, 0, stream>>>(x, theta, W1, b1, W2, W2f, W1f, Qfg);
  k_fused<<<(NTOK / BM) * (EMBED / BN), 512, 0, stream>>>(Qfg, W1f, W2f, b2, out);
}